// Round 5
// baseline (1402.971 us; speedup 1.0000x reference)
//
#include <hip/hip_runtime.h>
#include <hip/hip_bf16.h>

#define HID 64
#define NGRAPH 16
#define BN 32            // nodes per bucket
#define MAXNB 2048

// Fixed workspace layout (float offsets) — weights converted to fp32 + folded M,v
enum : int {
  OFF_V      = 1040,                  // [64]   v = eb2 @ nw1[1:]
  OFF_M      = 1104,                  // [4096] M = ew2 @ nw1[1:]
  OFF_EW1    = 5200,                  // [320]
  OFF_EB1    = 5520,                  // [64]
  OFF_NW1    = 5584,                  // [4160]
  OFF_NB1    = 9744,                  // [64]
  OFF_NW2    = 9808,                  // [4096]
  OFF_NB2    = 13904,                 // [64]
  OFF_OW1    = 13968,                 // [4096]
  OFF_OB1    = 18064,                 // [64]
  OFF_OW2    = 18128,                 // [4096]
  OFF_OB2    = 22224,                 // [64]
  OFF_OW3    = 22288,                 // [4096]
  OFF_OB3    = 26384,                 // [64]
  OFF_OW4    = 26448,                 // [128]
  OFF_OB4    = 26576,                 // [2]
  OFF_EW2    = 26578,                 // [4096]
  OFF_EB2    = 30674,                 // [64]
  OFF_FLAGS  = 30738,                 // 2 ints: [0]=ft (1=bf16), [1]=it (1=int64)
  OFF_PREP   = 30740                  // 8 pooled replicas * 16*64 = 8192 floats
};

struct WPtrs { const void* p[16]; };

__device__ __forceinline__ float cv(float v) { return v; }
__device__ __forceinline__ float cv(__hip_bfloat16 v) { return __bfloat162float(v); }

// ---------------------------------------------------------------------------
// prep: detect dtypes, convert weights to fp32, build folded M, v.
// ---------------------------------------------------------------------------
__global__ __launch_bounds__(256) void prep_kernel(
    const void* xv, const void* eiv, WPtrs wp, float* ws)
{
  __shared__ int red[2];
  __shared__ int s_ft;
  const int t = threadIdx.x;

  if (t == 0) { red[0] = 0; red[1] = 0; }
  __syncthreads();
  {
    const unsigned* u = (const unsigned*)xv;
    int big = 0;
    for (int i = t; i < 512; i += 256) {
      const unsigned el = (u[i] >> 7) & 0xFFu;
      big += (el >= 140u) ? 1 : 0;
    }
    atomicAdd(&red[0], big);
  }
  {
    const int* e32 = (const int*)eiv;
    int orv = 0;
    for (int i = 1 + 2 * t; i < 2048; i += 512) orv |= e32[i];
    atomicOr(&red[1], orv);
  }
  __syncthreads();
  if (t == 0) {
    const int ft = (red[0] < 8) ? 1 : 0;
    const int it = (red[1] == 0) ? 1 : 0;
    ((int*)(ws + OFF_FLAGS))[0] = ft;
    ((int*)(ws + OFF_FLAGS))[1] = it;
    s_ft = ft;
  }
  __syncthreads();
  const int ft = s_ft;

  const int sz[16]  = {320,64,4096,64,4160,64,4096,64,4096,64,4096,64,4096,64,128,2};
  const int dst[16] = {OFF_EW1,OFF_EB1,OFF_EW2,OFF_EB2,OFF_NW1,OFF_NB1,OFF_NW2,OFF_NB2,
                       OFF_OW1,OFF_OB1,OFF_OW2,OFF_OB2,OFF_OW3,OFF_OB3,OFF_OW4,OFF_OB4};
  for (int a = 0; a < 16; ++a) {
    const void* src = wp.p[a];
    float* d = ws + dst[a];
    const int n = sz[a];
    for (int i = t; i < n; i += 256)
      d[i] = ft ? __bfloat162float(((const __hip_bfloat16*)src)[i])
                : ((const float*)src)[i];
  }
  __syncthreads();

  __shared__ float ew2s[4096];
  __shared__ float nw1s[4096];
  for (int i = t; i < 4096; i += 256) {
    ew2s[i] = ws[OFF_EW2 + i];
    nw1s[i] = ws[OFF_NW1 + 64 + i];
  }
  __syncthreads();
  for (int idx = t; idx < 4096; idx += 256) {
    const int i = idx >> 6, j = idx & 63;
    float s = 0.0f;
    #pragma unroll 8
    for (int k = 0; k < 64; ++k)
      s = fmaf(ew2s[i * 64 + k], nw1s[k * 64 + j], s);
    ws[OFF_M + idx] = s;
  }
  for (int j = t; j < 64; j += 256) {
    float s = 0.0f;
    #pragma unroll 8
    for (int k = 0; k < 64; ++k)
      s = fmaf(ws[OFF_EB2 + k], nw1s[k * 64 + j], s);
    ws[OFF_V + j] = s;
  }
}

// ---------------------------------------------------------------------------
// hist: bucket counts via LDS histogram; one global atomic per (block,bucket).
// ---------------------------------------------------------------------------
template<typename IT>
__device__ __forceinline__ void hist_impl(
    const IT* __restrict__ ei, int* __restrict__ bstart, const int E, const int NB)
{
  __shared__ int lh[MAXNB];
  const int t = threadIdx.x;
  for (int i = t; i < NB; i += 256) lh[i] = 0;
  __syncthreads();
  const int stride = gridDim.x * 256;
  for (int e = blockIdx.x * 256 + t; e < E; e += stride) {
    const int c = (int)ei[(size_t)E + e];
    atomicAdd(&lh[c >> 5], 1);
  }
  __syncthreads();
  for (int b = t; b < NB; b += 256)
    if (lh[b]) atomicAdd(&bstart[b], lh[b]);
}

__global__ __launch_bounds__(256) void hist_kernel(
    const void* eiv, const float* ws, int* bstart, const int E, const int NB)
{
  const int it = ((const int*)(ws + OFF_FLAGS))[1];
  if (it) hist_impl<long long>((const long long*)eiv, bstart, E, NB);
  else    hist_impl<int>((const int*)eiv, bstart, E, NB);
}

// ---------------------------------------------------------------------------
// scan: exclusive prefix over NB bucket counts, in place; bcur = copy of starts.
// ---------------------------------------------------------------------------
__global__ __launch_bounds__(256) void scan_kernel(
    int* __restrict__ bstart, int* __restrict__ bcur, const int NB)
{
  __shared__ int ps[256];
  const int t = threadIdx.x;
  const int seg = (NB + 255) / 256;
  int s = 0;
  for (int i = 0; i < seg; ++i) {
    const int idx = t * seg + i;
    if (idx < NB) s += bstart[idx];
  }
  ps[t] = s;
  __syncthreads();
  for (int off = 1; off < 256; off <<= 1) {
    const int v = (t >= off) ? ps[t - off] : 0;
    __syncthreads();
    ps[t] += v;
    __syncthreads();
  }
  int carry = ps[t] - s;   // exclusive prefix
  for (int i = 0; i < seg; ++i) {
    const int idx = t * seg + i;
    if (idx < NB) {
      const int cnt = bstart[idx];
      bstart[idx] = carry;
      bcur[idx] = carry;
      carry += cnt;
    }
  }
  if (t == 255) bstart[NB] = ps[255];
}

// ---------------------------------------------------------------------------
// scatter: per-block tile -> LDS hist -> one global reserve atomic per
// (block,bucket) -> LDS-ranked scatter of edge ids. No per-edge global atomics.
// ---------------------------------------------------------------------------
template<typename IT>
__device__ __forceinline__ void scatter_impl(
    const IT* __restrict__ ei, int* __restrict__ bcur, int* __restrict__ seid,
    const int E, const int NB)
{
  __shared__ int lh[MAXNB];
  __shared__ int lb[MAXNB];
  const int t = threadIdx.x;
  const int per = (E + gridDim.x - 1) / gridDim.x;
  const int a = blockIdx.x * per;
  const int bnd = (a + per < E) ? (a + per) : E;

  for (int i = t; i < NB; i += 256) lh[i] = 0;
  __syncthreads();
  for (int e = a + t; e < bnd; e += 256) {
    const int c = (int)ei[(size_t)E + e];
    atomicAdd(&lh[c >> 5], 1);
  }
  __syncthreads();
  for (int b = t; b < NB; b += 256)
    lb[b] = lh[b] ? atomicAdd(&bcur[b], lh[b]) : 0;
  __syncthreads();
  for (int e = a + t; e < bnd; e += 256) {
    const int c = (int)ei[(size_t)E + e];
    const int pos = atomicAdd(&lb[c >> 5], 1);
    seid[pos] = e;
  }
}

__global__ __launch_bounds__(256) void scatter_kernel(
    const void* eiv, const float* ws, int* bcur, int* seid, const int E, const int NB)
{
  const int it = ((const int*)(ws + OFF_FLAGS))[1];
  if (it) scatter_impl<long long>((const long long*)eiv, bcur, seid, E, NB);
  else    scatter_impl<int>((const int*)eiv, bcur, seid, E, NB);
}

// ---------------------------------------------------------------------------
// fused: block b owns nodes [32b, 32b+32). Edge MLP hidden accumulated in an
// LDS tile (wave ds_add, zero global atomics), deg counted in LDS, then the
// folded node model (M matvec + relu) and pooled accumulation in LDS.
// Flush: ~1-2 rows per block into 8 global pooled replicas.
// ---------------------------------------------------------------------------
template<typename FT, typename IT>
__device__ __forceinline__ void fused_impl(
    const FT* __restrict__ x, const IT* __restrict__ ei, const FT* __restrict__ ea,
    const IT* __restrict__ batch, const float* __restrict__ ws,
    const int* __restrict__ bstart, const int* __restrict__ seid,
    float* __restrict__ rep, const int N, const int E)
{
  __shared__ float Msh[4096];
  __shared__ float agg[BN * 64];
  __shared__ float degL[BN];
  __shared__ float pooledL[NGRAPH * 64];
  __shared__ int gmin, gmax;

  const int t = threadIdx.x;
  const int lane = t & 63;
  const int wav = t >> 6;
  const int b = blockIdx.x;

  for (int i = t; i < 4096; i += 256) Msh[i] = ws[OFF_M + i];
  for (int i = t; i < BN * 64; i += 256) agg[i] = 0.0f;
  for (int i = t; i < NGRAPH * 64; i += 256) pooledL[i] = 0.0f;
  if (t < BN) degL[t] = 0.0f;
  if (t == 0) { gmin = 1 << 30; gmax = -1; }
  __syncthreads();

  // lane-resident ew1 columns + per-wave local x values
  const float w0 = ws[OFF_EW1 + 0 * HID + lane];
  const float w1 = ws[OFF_EW1 + 1 * HID + lane];
  const float w2 = ws[OFF_EW1 + 2 * HID + lane];
  const float w3 = ws[OFF_EW1 + 3 * HID + lane];
  const float w4 = ws[OFF_EW1 + 4 * HID + lane];
  const float b0 = ws[OFF_EB1 + lane];
  float xloc = 0.0f;
  { const int n = b * BN + (lane & 31); if (n < N) xloc = cv(x[n]); }

  const int start = bstart[b], end = bstart[b + 1];

  for (int base = start + wav * 64; base < end; base += 256) {
    const int m = (end - base < 64) ? (end - base) : 64;
    const int eid_l = (lane < m) ? seid[base + lane] : 0;
    const int r_l = (int)ei[eid_l];          // per-lane gather
    const float xr_l = cv(x[r_l]);           // per-lane gather

    if (m == 64) {
      #pragma unroll 4
      for (int k = 0; k < 64; ++k) {
        const int eid = __shfl(eid_l, k);
        const float xr = __shfl(xr_l, k);
        const int c = (int)ei[(size_t)E + eid];            // broadcast
        const float xc = __shfl(xloc, c & 31);
        const float a0 = cv(ea[(size_t)3 * eid + 0]);      // broadcast
        const float a1 = cv(ea[(size_t)3 * eid + 1]);
        const float a2 = cv(ea[(size_t)3 * eid + 2]);
        float h = fmaf(xr, w0, fmaf(xc, w1, fmaf(a0, w2, fmaf(a1, w3, fmaf(a2, w4, b0)))));
        h = fmaxf(h, 0.0f);
        atomicAdd(&agg[(c & 31) * 64 + lane], h);          // LDS wave atomic
        if (lane == 0) atomicAdd(&degL[c & 31], 1.0f);
      }
    } else {
      for (int k = 0; k < m; ++k) {
        const int eid = __shfl(eid_l, k);
        const float xr = __shfl(xr_l, k);
        const int c = (int)ei[(size_t)E + eid];
        const float xc = __shfl(xloc, c & 31);
        const float a0 = cv(ea[(size_t)3 * eid + 0]);
        const float a1 = cv(ea[(size_t)3 * eid + 1]);
        const float a2 = cv(ea[(size_t)3 * eid + 2]);
        float h = fmaf(xr, w0, fmaf(xc, w1, fmaf(a0, w2, fmaf(a1, w3, fmaf(a2, w4, b0)))));
        h = fmaxf(h, 0.0f);
        atomicAdd(&agg[(c & 31) * 64 + lane], h);
        if (lane == 0) atomicAdd(&degL[c & 31], 1.0f);
      }
    }
  }
  __syncthreads();

  // node model: wave handles 8 nodes
  const float c1 = ws[OFF_NW1 + lane];
  const float bb = ws[OFF_NB1 + lane];
  const float vv = ws[OFF_V + lane];

  for (int i = 0; i < 8; ++i) {
    const int nl = wav * 8 + i;
    const int n = b * BN + nl;
    if (n >= N) break;
    const float av = agg[nl * 64 + lane];
    float acc = 0.0f;
    #pragma unroll 16
    for (int k = 0; k < 64; ++k)
      acc = fmaf(__shfl(av, k), Msh[k * 64 + lane], acc);
    const float xn = __shfl(xloc, nl & 31);
    const float h = fmaxf(acc + xn * c1 + degL[nl] * vv + bb, 0.0f);
    const int g = (int)batch[n];
    atomicAdd(&pooledL[g * 64 + lane], h);
    if (lane == 0) { atomicMin(&gmin, g); atomicMax(&gmax, g); }
  }
  __syncthreads();

  float* myrep = rep + (size_t)(b & 7) * (NGRAPH * 64);
  for (int g = gmin + wav; g <= gmax; g += 4)
    unsafeAtomicAdd(&myrep[g * 64 + lane], pooledL[g * 64 + lane]);
}

__global__ __launch_bounds__(256) void fused_kernel(
    const void* xv, const void* eiv, const void* eav, const void* batv,
    const float* ws, const int* bstart, const int* seid, float* rep,
    const int N, const int E)
{
  const int* fl = (const int*)(ws + OFF_FLAGS);
  const int ft = fl[0], it = fl[1];
  if (ft) {
    if (it) fused_impl<__hip_bfloat16, long long>((const __hip_bfloat16*)xv, (const long long*)eiv, (const __hip_bfloat16*)eav, (const long long*)batv, ws, bstart, seid, rep, N, E);
    else    fused_impl<__hip_bfloat16, int>((const __hip_bfloat16*)xv, (const int*)eiv, (const __hip_bfloat16*)eav, (const int*)batv, ws, bstart, seid, rep, N, E);
  } else {
    if (it) fused_impl<float, long long>((const float*)xv, (const long long*)eiv, (const float*)eav, (const long long*)batv, ws, bstart, seid, rep, N, E);
    else    fused_impl<float, int>((const float*)xv, (const int*)eiv, (const float*)eav, (const int*)batv, ws, bstart, seid, rep, N, E);
  }
}

// ---------------------------------------------------------------------------
// head: reduce 8 pooled replicas, recompute cnt from batch, then
// pooled@nw2 + cnt*nb2, 3x (Linear+ReLU), Linear(64,2).
// ---------------------------------------------------------------------------
__global__ __launch_bounds__(256) void head_kernel(
    const float* ws, const float* rep, const void* batv, void* outv, const int N)
{
  __shared__ float P[NGRAPH][HID];
  __shared__ float A[NGRAPH][HID];
  __shared__ float B[NGRAPH][HID];
  __shared__ float cntL[NGRAPH];

  const int t = threadIdx.x;
  const int j = t & 63;
  const int gq = t >> 6;

  if (t < NGRAPH) cntL[t] = 0.0f;
  __syncthreads();

  const int it = ((const int*)(ws + OFF_FLAGS))[1];
  if (it) {
    const long long* bt = (const long long*)batv;
    for (int i = t; i < N; i += 256) atomicAdd(&cntL[(int)bt[i]], 1.0f);
  } else {
    const int* bt = (const int*)batv;
    for (int i = t; i < N; i += 256) atomicAdd(&cntL[bt[i]], 1.0f);
  }

  #pragma unroll
  for (int gi = 0; gi < 4; ++gi) {
    const int g = gq + gi * 4;
    float s = 0.0f;
    #pragma unroll
    for (int r = 0; r < 8; ++r)
      s += rep[(size_t)r * (NGRAPH * 64) + g * 64 + j];
    P[g][j] = s;
  }
  __syncthreads();

  {
    const float bj = ws[OFF_NB2 + j];
    #pragma unroll
    for (int gi = 0; gi < 4; ++gi) {
      const int g = gq + gi * 4;
      float s = cntL[g] * bj;
      #pragma unroll 8
      for (int k = 0; k < HID; ++k)
        s = fmaf(P[g][k], ws[OFF_NW2 + k * HID + j], s);
      A[g][j] = s;
    }
  }
  __syncthreads();

  const int wOff[3] = {OFF_OW1, OFF_OW2, OFF_OW3};
  const int bOff[3] = {OFF_OB1, OFF_OB2, OFF_OB3};
  for (int L = 0; L < 3; ++L) {
    float (*In)[HID]  = (L & 1) ? B : A;
    float (*Out)[HID] = (L & 1) ? A : B;
    const float bj = ws[bOff[L] + j];
    #pragma unroll
    for (int gi = 0; gi < 4; ++gi) {
      const int g = gq + gi * 4;
      float s = bj;
      #pragma unroll 8
      for (int k = 0; k < HID; ++k)
        s = fmaf(In[g][k], ws[wOff[L] + k * HID + j], s);
      Out[g][j] = fmaxf(s, 0.0f);
    }
    __syncthreads();
  }

  if (t < 32) {
    const int g = t >> 1, d = t & 1;
    float s = ws[OFF_OB4 + d];
    #pragma unroll 8
    for (int k = 0; k < HID; ++k)
      s = fmaf(B[g][k], ws[OFF_OW4 + k * 2 + d], s);
    const int ft = ((const int*)(ws + OFF_FLAGS))[0];
    if (ft) ((__hip_bfloat16*)outv)[g * 2 + d] = __float2bfloat16(s);
    else    ((float*)outv)[g * 2 + d] = s;
  }
}

extern "C" void kernel_launch(void* const* d_in, const int* in_sizes, int n_in,
                              void* d_out, int out_size, void* d_ws, size_t ws_size,
                              hipStream_t stream)
{
  const void* xv   = d_in[0];
  const void* eiv  = d_in[1];
  const void* eav  = d_in[2];
  const void* batv = d_in[3];

  WPtrs wp;
  for (int a = 0; a < 16; ++a) wp.p[a] = d_in[4 + a];

  const int N = in_sizes[0];
  const int E = in_sizes[1] / 2;
  const int NB = (N + BN - 1) / BN;
  if (NB > MAXNB) return;

  float* ws  = (float*)d_ws;
  float* rep = ws + OFF_PREP;                       // 8*1024 floats
  int* bstart = (int*)(ws + OFF_PREP + 8 * NGRAPH * 64);  // NB+1 ints
  int* bcur   = bstart + NB + 1;                    // NB ints
  int* seid   = bcur + NB;                          // E ints

  const size_t needBytes =
      ((size_t)(OFF_PREP + 8 * NGRAPH * 64) + (size_t)(2 * NB + 1) + (size_t)E) * 4;
  if (ws_size < needBytes) return;

  // zero pooled replicas + bstart (contiguous region)
  hipMemsetAsync(rep, 0, (size_t)(8 * NGRAPH * 64 + NB + 1) * 4, stream);

  prep_kernel<<<1, 256, 0, stream>>>(xv, eiv, wp, ws);
  hist_kernel<<<32, 256, 0, stream>>>(eiv, ws, bstart, E, NB);
  scan_kernel<<<1, 256, 0, stream>>>(bstart, bcur, NB);
  scatter_kernel<<<64, 256, 0, stream>>>(eiv, ws, bcur, seid, E, NB);
  fused_kernel<<<NB, 256, 0, stream>>>(xv, eiv, eav, batv, ws, bstart, seid, rep, N, E);
  head_kernel<<<1, 256, 0, stream>>>(ws, rep, batv, d_out, N);
}

// Round 7
// 1078.807 us; speedup vs baseline: 1.3005x; 1.3005x over previous
//
#include <hip/hip_runtime.h>
#include <hip/hip_bf16.h>

#define HID 64
#define NGRAPH 16
#define BN 32            // nodes per bucket
#define MAXNB 2048
#define NCB 64           // count/scatter blocks

// Fixed workspace layout (float offsets) — weights converted to fp32 + folded M,v
enum : int {
  OFF_V      = 1040,                  // [64]   v = eb2 @ nw1[1:]
  OFF_M      = 1104,                  // [4096] M = ew2 @ nw1[1:]
  OFF_EW1    = 5200,                  // [320]
  OFF_EB1    = 5520,                  // [64]
  OFF_NW1    = 5584,                  // [4160]
  OFF_NB1    = 9744,                  // [64]
  OFF_NW2    = 9808,                  // [4096]
  OFF_NB2    = 13904,                 // [64]
  OFF_OW1    = 13968,                 // [4096]
  OFF_OB1    = 18064,                 // [64]
  OFF_OW2    = 18128,                 // [4096]
  OFF_OB2    = 22224,                 // [64]
  OFF_OW3    = 22288,                 // [4096]
  OFF_OB3    = 26384,                 // [64]
  OFF_OW4    = 26448,                 // [128]
  OFF_OB4    = 26576,                 // [2]
  OFF_EW2    = 26578,                 // [4096]
  OFF_EB2    = 30674,                 // [64]
  OFF_FLAGS  = 30738,                 // 2 ints: [0]=ft (1=bf16), [1]=it (1=int64)
  OFF_PREP   = 30740                  // rep: 8 pooled replicas * 16*64
};

struct WPtrs { const void* p[16]; };

__device__ __forceinline__ float cv(float v) { return v; }
__device__ __forceinline__ float cv(__hip_bfloat16 v) { return __bfloat162float(v); }

// ---------------------------------------------------------------------------
// prep: detect dtypes, convert weights to fp32, build folded M, v.
// ---------------------------------------------------------------------------
__global__ __launch_bounds__(256) void prep_kernel(
    const void* xv, const void* eiv, WPtrs wp, float* ws)
{
  __shared__ int red[2];
  __shared__ int s_ft;
  __shared__ float ew2s[4096];
  __shared__ float nw1s[4096];
  const int t = threadIdx.x;

  if (t == 0) { red[0] = 0; red[1] = 0; }
  __syncthreads();
  {
    const unsigned* u = (const unsigned*)xv;
    int big = 0;
    for (int i = t; i < 512; i += 256) {
      const unsigned el = (u[i] >> 7) & 0xFFu;
      big += (el >= 140u) ? 1 : 0;
    }
    atomicAdd(&red[0], big);
  }
  {
    const int* e32 = (const int*)eiv;
    int orv = 0;
    for (int i = 1 + 2 * t; i < 2048; i += 512) orv |= e32[i];
    atomicOr(&red[1], orv);
  }
  __syncthreads();
  if (t == 0) {
    const int ft = (red[0] < 8) ? 1 : 0;
    const int it = (red[1] == 0) ? 1 : 0;
    ((int*)(ws + OFF_FLAGS))[0] = ft;
    ((int*)(ws + OFF_FLAGS))[1] = it;
    s_ft = ft;
  }
  __syncthreads();
  const int ft = s_ft;

  const int sz[16]  = {320,64,4096,64,4160,64,4096,64,4096,64,4096,64,4096,64,128,2};
  const int dst[16] = {OFF_EW1,OFF_EB1,OFF_EW2,OFF_EB2,OFF_NW1,OFF_NB1,OFF_NW2,OFF_NB2,
                       OFF_OW1,OFF_OB1,OFF_OW2,OFF_OB2,OFF_OW3,OFF_OB3,OFF_OW4,OFF_OB4};
  for (int a = 0; a < 16; ++a) {
    const void* src = wp.p[a];
    float* d = ws + dst[a];
    const int n = sz[a];
    for (int i = t; i < n; i += 256)
      d[i] = ft ? __bfloat162float(((const __hip_bfloat16*)src)[i])
                : ((const float*)src)[i];
  }
  __syncthreads();

  for (int i = t; i < 4096; i += 256) {
    ew2s[i] = ws[OFF_EW2 + i];
    nw1s[i] = ws[OFF_NW1 + 64 + i];
  }
  __syncthreads();
  for (int idx = t; idx < 4096; idx += 256) {
    const int i = idx >> 6, j = idx & 63;
    float s = 0.0f;
    #pragma unroll 8
    for (int k = 0; k < 64; ++k)
      s = fmaf(ew2s[i * 64 + k], nw1s[k * 64 + j], s);
    ws[OFF_M + idx] = s;
  }
  for (int j = t; j < 64; j += 256) {
    float s = 0.0f;
    #pragma unroll 8
    for (int k = 0; k < 64; ++k)
      s = fmaf(ws[OFF_EB2 + k], nw1s[k * 64 + j], s);
    ws[OFF_V + j] = s;
  }
}

// ---------------------------------------------------------------------------
// count: per-block LDS histogram of its edge window; plain coalesced stores
// to gcnt[block][bucket]. Zero global atomics.
// ---------------------------------------------------------------------------
template<typename IT>
__device__ __forceinline__ void count_impl(
    const IT* __restrict__ ei, int* __restrict__ gcnt, int* lh,
    const int E, const int NB)
{
  const int t = threadIdx.x;
  const int b = blockIdx.x;
  for (int i = t; i < NB; i += 256) lh[i] = 0;
  __syncthreads();
  const int per = (E + NCB - 1) / NCB;
  const int a = b * per;
  const int bnd = (a + per < E) ? (a + per) : E;
  for (int e = a + t; e < bnd; e += 256) {
    const int c = (int)ei[(size_t)E + e];
    atomicAdd(&lh[c >> 5], 1);
  }
  __syncthreads();
  for (int i = t; i < NB; i += 256) gcnt[b * NB + i] = lh[i];
}

__global__ __launch_bounds__(256) void count_kernel(
    const void* eiv, const float* ws, int* gcnt, const int E, const int NB)
{
  __shared__ int lh[MAXNB];
  const int it = ((const int*)(ws + OFF_FLAGS))[1];
  if (it) count_impl<long long>((const long long*)eiv, gcnt, lh, E, NB);
  else    count_impl<int>((const int*)eiv, gcnt, lh, E, NB);
}

// ---------------------------------------------------------------------------
// scan: bucket totals -> exclusive prefix (bstart) -> rewrite gcnt to absolute
// per-(block,bucket) start offsets. Single block.
// ---------------------------------------------------------------------------
__global__ __launch_bounds__(256) void scan_kernel(
    int* __restrict__ gcnt, int* __restrict__ bstart, const int NB)
{
  __shared__ int ps[256];
  const int t = threadIdx.x;

  for (int bkt = t; bkt < NB; bkt += 256) {
    int s = 0;
    for (int blk = 0; blk < NCB; ++blk) s += gcnt[blk * NB + bkt];
    bstart[bkt] = s;
  }
  __syncthreads();

  const int seg = (NB + 255) / 256;
  int s = 0;
  for (int i = 0; i < seg; ++i) {
    const int idx = t * seg + i;
    if (idx < NB) s += bstart[idx];
  }
  ps[t] = s;
  __syncthreads();
  for (int off = 1; off < 256; off <<= 1) {
    const int v = (t >= off) ? ps[t - off] : 0;
    __syncthreads();
    ps[t] += v;
    __syncthreads();
  }
  int carry = ps[t] - s;
  for (int i = 0; i < seg; ++i) {
    const int idx = t * seg + i;
    if (idx < NB) {
      const int tot = bstart[idx];
      bstart[idx] = carry;
      int run = carry;
      for (int blk = 0; blk < NCB; ++blk) {
        const int c2 = gcnt[blk * NB + idx];
        gcnt[blk * NB + idx] = run;
        run += c2;
      }
      carry += tot;
    }
  }
  if (t == 255) bstart[NB] = ps[255];
}

// ---------------------------------------------------------------------------
// scatter: block b loads its absolute offsets into LDS cursors (lb), then
// ranks each edge with an LDS atomic and stores its id to seid (global).
// Zero global atomics.  NOTE param order: (ei, gcnt, lb, seid, E, NB) —
// round-6 crash was lb/seid swapped at the call site (LDS OOB write).
// ---------------------------------------------------------------------------
template<typename IT>
__device__ __forceinline__ void scatter_impl(
    const IT* __restrict__ ei, const int* __restrict__ gcnt,
    int* lb, int* __restrict__ seid, const int E, const int NB)
{
  const int t = threadIdx.x;
  const int b = blockIdx.x;
  for (int i = t; i < NB; i += 256) lb[i] = gcnt[b * NB + i];
  __syncthreads();
  const int per = (E + NCB - 1) / NCB;
  const int a = b * per;
  const int bnd = (a + per < E) ? (a + per) : E;
  for (int e = a + t; e < bnd; e += 256) {
    const int c = (int)ei[(size_t)E + e];
    const int pos = atomicAdd(&lb[c >> 5], 1);
    seid[pos] = e;
  }
}

__global__ __launch_bounds__(256) void scatter_kernel(
    const void* eiv, const float* ws, const int* gcnt, int* seid,
    const int E, const int NB)
{
  __shared__ int lb[MAXNB];
  const int it = ((const int*)(ws + OFF_FLAGS))[1];
  if (it) scatter_impl<long long>((const long long*)eiv, gcnt, lb, seid, E, NB);
  else    scatter_impl<int>((const int*)eiv, gcnt, lb, seid, E, NB);
}

// ---------------------------------------------------------------------------
// fused: block b owns nodes [32b, 32b+32). Chunked cooperative staging of 256
// edges into LDS (parallel gathers), then waves consume 64 each: lane j =
// feature j, LDS atomic into the 32x64 agg tile. Then folded node model
// (M matvec + relu) and pooled accumulation in LDS; tiny replica flush.
// ---------------------------------------------------------------------------
template<typename FT, typename IT>
__device__ __forceinline__ void fused_impl(
    const FT* __restrict__ x, const IT* __restrict__ ei, const FT* __restrict__ ea,
    const IT* __restrict__ batch, const float* __restrict__ ws,
    const int* __restrict__ bstart, const int* __restrict__ seid,
    float* __restrict__ rep,
    float* Msh, float* agg, float* pooledL, float* degL, float* xls,
    float* sxr, float* sa0, float* sa1, float* sa2, int* scid, int* gmm,
    const int N, const int E)
{
  const int t = threadIdx.x;
  const int lane = t & 63;
  const int wav = t >> 6;
  const int b = blockIdx.x;

  for (int i = t; i < 4096; i += 256) Msh[i] = ws[OFF_M + i];
  for (int i = t; i < BN * 64; i += 256) agg[i] = 0.0f;
  for (int i = t; i < NGRAPH * 64; i += 256) pooledL[i] = 0.0f;
  if (t < BN) {
    degL[t] = 0.0f;
    const int n = b * BN + t;
    xls[t] = (n < N) ? cv(x[n]) : 0.0f;
  }
  if (t == 0) { gmm[0] = 1 << 30; gmm[1] = -1; }
  __syncthreads();

  const float w0 = ws[OFF_EW1 + 0 * HID + lane];
  const float w1 = ws[OFF_EW1 + 1 * HID + lane];
  const float w2 = ws[OFF_EW1 + 2 * HID + lane];
  const float w3 = ws[OFF_EW1 + 3 * HID + lane];
  const float w4 = ws[OFF_EW1 + 4 * HID + lane];
  const float b0 = ws[OFF_EB1 + lane];

  const int start = bstart[b], end = bstart[b + 1];

  for (int base = start; base < end; base += 256) {
    const int m = (end - base < 256) ? (end - base) : 256;
    // stage (parallel gathers by all 256 threads)
    if (t < m) {
      const int eid = seid[base + t];
      const int r = (int)ei[eid];
      const int c = (int)ei[(size_t)E + eid];
      sxr[t] = cv(x[r]);
      scid[t] = c & 31;
      sa0[t] = cv(ea[(size_t)3 * eid + 0]);
      sa1[t] = cv(ea[(size_t)3 * eid + 1]);
      sa2[t] = cv(ea[(size_t)3 * eid + 2]);
      atomicAdd(&degL[c & 31], 1.0f);
    }
    __syncthreads();
    // consume: wave w handles staged edges [w*64, w*64+64)
    const int e0 = wav * 64;
    int mm = m - e0; if (mm > 64) mm = 64;
    for (int k = 0; k < mm; ++k) {
      const int kk = e0 + k;
      const int cL = scid[kk];               // LDS broadcast
      const float xc = xls[cL];
      float h = fmaf(sxr[kk], w0, fmaf(xc, w1,
                fmaf(sa0[kk], w2, fmaf(sa1[kk], w3, fmaf(sa2[kk], w4, b0)))));
      h = fmaxf(h, 0.0f);
      atomicAdd(&agg[cL * 64 + lane], h);    // LDS wave atomic, conflict-free
    }
    __syncthreads();
  }

  // node model: wave handles 8 nodes
  const float c1 = ws[OFF_NW1 + lane];
  const float bb = ws[OFF_NB1 + lane];
  const float vv = ws[OFF_V + lane];

  for (int i = 0; i < 8; ++i) {
    const int nl = wav * 8 + i;
    const int n = b * BN + nl;
    if (n >= N) break;
    const float av = agg[nl * 64 + lane];
    float acc = 0.0f;
    #pragma unroll 16
    for (int k = 0; k < 64; ++k)
      acc = fmaf(__shfl(av, k), Msh[k * 64 + lane], acc);
    const float h = fmaxf(acc + xls[nl] * c1 + degL[nl] * vv + bb, 0.0f);
    const int g = (int)batch[n];
    atomicAdd(&pooledL[g * 64 + lane], h);
    if (lane == 0) { atomicMin(&gmm[0], g); atomicMax(&gmm[1], g); }
  }
  __syncthreads();

  float* myrep = rep + (size_t)(b & 7) * (NGRAPH * 64);
  for (int g = gmm[0] + wav; g <= gmm[1]; g += 4)
    unsafeAtomicAdd(&myrep[g * 64 + lane], pooledL[g * 64 + lane]);
}

__global__ __launch_bounds__(256) void fused_kernel(
    const void* xv, const void* eiv, const void* eav, const void* batv,
    const float* ws, const int* bstart, const int* seid, float* rep,
    const int N, const int E)
{
  // All LDS hoisted here: ONE copy regardless of template instantiations.
  __shared__ float Msh[4096];
  __shared__ float agg[BN * 64];
  __shared__ float pooledL[NGRAPH * 64];
  __shared__ float degL[BN];
  __shared__ float xls[BN];
  __shared__ float sxr[256], sa0[256], sa1[256], sa2[256];
  __shared__ int   scid[256];
  __shared__ int   gmm[2];

  const int* fl = (const int*)(ws + OFF_FLAGS);
  const int ft = fl[0], it = fl[1];
  if (ft) {
    if (it) fused_impl<__hip_bfloat16, long long>((const __hip_bfloat16*)xv, (const long long*)eiv, (const __hip_bfloat16*)eav, (const long long*)batv, ws, bstart, seid, rep, Msh, agg, pooledL, degL, xls, sxr, sa0, sa1, sa2, scid, gmm, N, E);
    else    fused_impl<__hip_bfloat16, int>((const __hip_bfloat16*)xv, (const int*)eiv, (const __hip_bfloat16*)eav, (const int*)batv, ws, bstart, seid, rep, Msh, agg, pooledL, degL, xls, sxr, sa0, sa1, sa2, scid, gmm, N, E);
  } else {
    if (it) fused_impl<float, long long>((const float*)xv, (const long long*)eiv, (const float*)eav, (const long long*)batv, ws, bstart, seid, rep, Msh, agg, pooledL, degL, xls, sxr, sa0, sa1, sa2, scid, gmm, N, E);
    else    fused_impl<float, int>((const float*)xv, (const int*)eiv, (const float*)eav, (const int*)batv, ws, bstart, seid, rep, Msh, agg, pooledL, degL, xls, sxr, sa0, sa1, sa2, scid, gmm, N, E);
  }
}

// ---------------------------------------------------------------------------
// head: reduce 8 pooled replicas, recompute cnt from batch, then
// pooled@nw2 + cnt*nb2, 3x (Linear+ReLU), Linear(64,2).
// ---------------------------------------------------------------------------
__global__ __launch_bounds__(256) void head_kernel(
    const float* ws, const float* rep, const void* batv, void* outv, const int N)
{
  __shared__ float P[NGRAPH][HID];
  __shared__ float A[NGRAPH][HID];
  __shared__ float B[NGRAPH][HID];
  __shared__ float cntL[NGRAPH];

  const int t = threadIdx.x;
  const int j = t & 63;
  const int gq = t >> 6;

  if (t < NGRAPH) cntL[t] = 0.0f;
  __syncthreads();

  const int it = ((const int*)(ws + OFF_FLAGS))[1];
  if (it) {
    const long long* bt = (const long long*)batv;
    for (int i = t; i < N; i += 256) atomicAdd(&cntL[(int)bt[i]], 1.0f);
  } else {
    const int* bt = (const int*)batv;
    for (int i = t; i < N; i += 256) atomicAdd(&cntL[bt[i]], 1.0f);
  }

  #pragma unroll
  for (int gi = 0; gi < 4; ++gi) {
    const int g = gq + gi * 4;
    float s = 0.0f;
    #pragma unroll
    for (int r = 0; r < 8; ++r)
      s += rep[(size_t)r * (NGRAPH * 64) + g * 64 + j];
    P[g][j] = s;
  }
  __syncthreads();

  {
    const float bj = ws[OFF_NB2 + j];
    #pragma unroll
    for (int gi = 0; gi < 4; ++gi) {
      const int g = gq + gi * 4;
      float s = cntL[g] * bj;
      #pragma unroll 8
      for (int k = 0; k < HID; ++k)
        s = fmaf(P[g][k], ws[OFF_NW2 + k * HID + j], s);
      A[g][j] = s;
    }
  }
  __syncthreads();

  const int wOff[3] = {OFF_OW1, OFF_OW2, OFF_OW3};
  const int bOff[3] = {OFF_OB1, OFF_OB2, OFF_OB3};
  for (int L = 0; L < 3; ++L) {
    float (*In)[HID]  = (L & 1) ? B : A;
    float (*Out)[HID] = (L & 1) ? A : B;
    const float bj = ws[bOff[L] + j];
    #pragma unroll
    for (int gi = 0; gi < 4; ++gi) {
      const int g = gq + gi * 4;
      float s = bj;
      #pragma unroll 8
      for (int k = 0; k < HID; ++k)
        s = fmaf(In[g][k], ws[wOff[L] + k * HID + j], s);
      Out[g][j] = fmaxf(s, 0.0f);
    }
    __syncthreads();
  }

  if (t < 32) {
    const int g = t >> 1, d = t & 1;
    float s = ws[OFF_OB4 + d];
    #pragma unroll 8
    for (int k = 0; k < HID; ++k)
      s = fmaf(B[g][k], ws[OFF_OW4 + k * 2 + d], s);
    const int ft = ((const int*)(ws + OFF_FLAGS))[0];
    if (ft) ((__hip_bfloat16*)outv)[g * 2 + d] = __float2bfloat16(s);
    else    ((float*)outv)[g * 2 + d] = s;
  }
}

extern "C" void kernel_launch(void* const* d_in, const int* in_sizes, int n_in,
                              void* d_out, int out_size, void* d_ws, size_t ws_size,
                              hipStream_t stream)
{
  const void* xv   = d_in[0];
  const void* eiv  = d_in[1];
  const void* eav  = d_in[2];
  const void* batv = d_in[3];

  WPtrs wp;
  for (int a = 0; a < 16; ++a) wp.p[a] = d_in[4 + a];

  const int N = in_sizes[0];
  const int E = in_sizes[1] / 2;
  const int NB = (N + BN - 1) / BN;
  if (NB > MAXNB) return;

  float* ws  = (float*)d_ws;
  float* rep = ws + OFF_PREP;                              // 8*1024 floats
  int* bstart = (int*)(ws + OFF_PREP + 8 * NGRAPH * 64);   // NB+1 ints
  int* gcnt   = bstart + NB + 1;                           // NCB*NB ints
  int* seid   = gcnt + (size_t)NCB * NB;                   // E ints

  const size_t needBytes =
      ((size_t)(OFF_PREP + 8 * NGRAPH * 64) +
       (size_t)(NB + 1) + (size_t)NCB * NB + (size_t)E) * 4;
  if (ws_size < needBytes) return;

  hipMemsetAsync(rep, 0, (size_t)(8 * NGRAPH * 64) * 4, stream);

  prep_kernel<<<1, 256, 0, stream>>>(xv, eiv, wp, ws);
  count_kernel<<<NCB, 256, 0, stream>>>(eiv, ws, gcnt, E, NB);
  scan_kernel<<<1, 256, 0, stream>>>(gcnt, bstart, NB);
  scatter_kernel<<<NCB, 256, 0, stream>>>(eiv, ws, gcnt, seid, E, NB);
  fused_kernel<<<NB, 256, 0, stream>>>(xv, eiv, eav, batv, ws, bstart, seid, rep, N, E);
  head_kernel<<<1, 256, 0, stream>>>(ws, rep, batv, d_out, N);
}